// Round 7
// baseline (157.459 us; speedup 1.0000x reference)
//
#include <hip/hip_runtime.h>

// MoE-LoRA top-1 dispatch, two-pass:
//  cvtx_pool: x f32 -> x_bf (bf16) + pool partials   [pure stream, no barriers]
//  xe:        x_bf @ A^T per expert -> xr bf16       [bf16 MFMA, light staging]
//  router: partials -> MLP -> top/balance ; out: xr[top[b]] @ B^T * 2
constexpr int B_ = 4, S_ = 2048, D_ = 4096, E_ = 4, R_ = 64, OUT_ = 4096;
constexpr int NMOD = 4, NREG = 3, HID_ = 128;
constexpr int RIN_ = D_ + NMOD + NREG;      // 4103
constexpr float SCALING_ = 2.0f;            // alpha/rank
constexpr int NSB_ = 128;                   // cvtx strips of 16 rows (pool partial count)
constexpr int KC_  = 33;                    // router k-chunks of 128 (33*128 >= 4103)

// ws layout (float units) — everything fully written each call, no memset needed
constexpr size_t WS_PP    = 0;                                     // NSB_*B*D f32 pool partials
constexpr size_t WS_HACC2 = WS_PP + (size_t)NSB_ * B_ * D_;        // B*KC_*HID f32
constexpr size_t WS_TOP   = WS_HACC2 + B_ * KC_ * HID_;            // B ints
constexpr size_t WS_ABF   = WS_TOP + 16;                           // E*R*D bf16
constexpr size_t WS_BBF   = WS_ABF + (size_t)E_ * R_ * D_ / 2;     // E*OUT*R bf16
constexpr size_t WS_XRB   = WS_BBF + (size_t)E_ * OUT_ * R_ / 2;   // E*B*S*R bf16
constexpr size_t WS_XBF   = WS_XRB + (size_t)E_ * B_ * S_ * R_ / 2;// B*S*D bf16

using short8 = __attribute__((ext_vector_type(8))) short;
using f32x4  = __attribute__((ext_vector_type(4))) float;

__device__ inline unsigned short f2bf(float f) {  // RNE fp32 -> bf16
    unsigned u = __float_as_uint(f);
    unsigned r = u + 0x7FFFu + ((u >> 16) & 1u);
    return (unsigned short)(r >> 16);
}

__global__ void cvt_w_kernel(const float* __restrict__ A, const float* __restrict__ Bw,
                             ushort* __restrict__ Abf, ushort* __restrict__ Bbf) {
    int i = blockIdx.x * blockDim.x + threadIdx.x;  // float4 id
    constexpr int N4 = E_ * R_ * D_ / 4;            // 262144 per tensor
    if (i < N4) {
        float4 v = ((const float4*)A)[i];
        ((ushort4*)Abf)[i] = make_ushort4(f2bf(v.x), f2bf(v.y), f2bf(v.z), f2bf(v.w));
    } else {
        int j = i - N4;
        float4 v = ((const float4*)Bw)[j];
        ((ushort4*)Bbf)[j] = make_ushort4(f2bf(v.x), f2bf(v.y), f2bf(v.z), f2bf(v.w));
    }
}

// Stream x: f32 -> bf16, plus per-strip pool column sums (16 rows / strip).
// No barriers, no shuffles: thread t owns column-quads t and t+512.
__global__ __launch_bounds__(512) void cvtx_pool_kernel(const float* __restrict__ x,
                                                        ushort* __restrict__ xbf,
                                                        float* __restrict__ pp) {
    int sb = blockIdx.x, b = blockIdx.y;
    int s0 = sb * 16;
    int t = threadIdx.x;
    const float4* xp = (const float4*)(x + ((size_t)b * S_ + s0) * D_);
    ushort4*      xo = (ushort4*)(xbf + ((size_t)b * S_ + s0) * D_);
    float4 a0 = {0.f, 0.f, 0.f, 0.f}, a1 = {0.f, 0.f, 0.f, 0.f};
#pragma unroll 4
    for (int r = 0; r < 16; ++r) {
        float4 v0 = xp[(size_t)r * 1024 + t];
        float4 v1 = xp[(size_t)r * 1024 + t + 512];
        a0.x += v0.x; a0.y += v0.y; a0.z += v0.z; a0.w += v0.w;
        a1.x += v1.x; a1.y += v1.y; a1.z += v1.z; a1.w += v1.w;
        xo[(size_t)r * 1024 + t]       = make_ushort4(f2bf(v0.x), f2bf(v0.y), f2bf(v0.z), f2bf(v0.w));
        xo[(size_t)r * 1024 + t + 512] = make_ushort4(f2bf(v1.x), f2bf(v1.y), f2bf(v1.z), f2bf(v1.w));
    }
    float* ppb = pp + ((size_t)sb * B_ + b) * D_;
    *(float4*)&ppb[t * 4]         = a0;
    *(float4*)&ppb[(t + 512) * 4] = a1;
}

// Block = (sb, b, e): 64 s-rows x full D for ONE expert; 8 waves; BK=128.
// Wave w: m-tile m=w&3, n-pair p=w>>2. Next-chunk loads issued before MFMA.
__global__ __launch_bounds__(512, 2) void xe_kernel(const ushort* __restrict__ xbf,
                                                    const ushort* __restrict__ Abf,
                                                    ushort* __restrict__ xr_bf) {
    __shared__ ushort xs[64][136];      // 272B row stride (17x16B, odd) -> benign b128 pattern
    __shared__ ushort as[64][136];
    int sb = blockIdx.x, b = blockIdx.y, e = blockIdx.z;
    int s0 = sb * 64;
    int t = threadIdx.x, lane = t & 63, w = t >> 6;
    int m = w & 3, p = w >> 2;
    const ushort* xb = xbf + ((size_t)b * S_ + s0) * D_;
    const ushort* Ab = Abf + (size_t)e * R_ * D_;
    int r0 = t >> 4, oc = t & 15;       // rows r0, r0+32 ; col-oct oc (8 bf16 = 16B)
    // prologue: chunk kc=0
    int4 xv0 = *(const int4*)(xb + (size_t)r0 * D_ + oc * 8);
    int4 xv1 = *(const int4*)(xb + (size_t)(r0 + 32) * D_ + oc * 8);
    int4 av0 = *(const int4*)(Ab + (size_t)r0 * D_ + oc * 8);
    int4 av1 = *(const int4*)(Ab + (size_t)(r0 + 32) * D_ + oc * 8);
    f32x4 acc[2] = {};
    int mrow = m * 16 + (lane & 15);
    int koff = (lane >> 4) * 8;
    for (int kc = 0; kc < D_ / 128; ++kc) {
        __syncthreads();               // previous tile's readers done
        *(int4*)&xs[r0][oc * 8]      = xv0;
        *(int4*)&xs[r0 + 32][oc * 8] = xv1;
        *(int4*)&as[r0][oc * 8]      = av0;
        *(int4*)&as[r0 + 32][oc * 8] = av1;
        __syncthreads();               // tile ready
        if (kc < D_ / 128 - 1) {       // issue next-chunk loads; in flight across MFMA
            int k0 = (kc + 1) * 128;
            xv0 = *(const int4*)(xb + (size_t)r0 * D_ + k0 + oc * 8);
            xv1 = *(const int4*)(xb + (size_t)(r0 + 32) * D_ + k0 + oc * 8);
            av0 = *(const int4*)(Ab + (size_t)r0 * D_ + k0 + oc * 8);
            av1 = *(const int4*)(Ab + (size_t)(r0 + 32) * D_ + k0 + oc * 8);
        }
#pragma unroll
        for (int kf = 0; kf < 4; ++kf) {
            short8 af = *(const short8*)&xs[mrow][kf * 32 + koff];
#pragma unroll
            for (int n = 0; n < 2; ++n) {
                short8 bf = *(const short8*)&as[(p * 2 + n) * 16 + (lane & 15)][kf * 32 + koff];
                acc[n] = __builtin_amdgcn_mfma_f32_16x16x32_bf16(af, bf, acc[n], 0, 0, 0);
            }
        }
    }
    // C/D: col = lane&15, row = (lane>>4)*4 + i ; write bf16 xr directly
    int col0 = lane & 15;
    int rb   = m * 16 + ((lane >> 4) << 2);
    ushort* xo = xr_bf + (((size_t)e * B_ + b) * S_ + s0) * R_;
#pragma unroll
    for (int n = 0; n < 2; ++n)
#pragma unroll
        for (int i = 0; i < 4; ++i)
            xo[(size_t)(rb + i) * R_ + (p * 2 + n) * 16 + col0] = f2bf(acc[n][i]);
}

// hacc2[b][kc][h] = sum over chunk's 128 k-rows of router_in[k]*w1[k][h]
__global__ __launch_bounds__(256) void router_h_kernel(const float* __restrict__ pp,
                                                       const float* __restrict__ rel,
                                                       const float* __restrict__ reg,
                                                       const float* __restrict__ w1,
                                                       float* __restrict__ hacc2) {
    __shared__ float rin[128];
    __shared__ float red[256];
    int b = blockIdx.x, kc = blockIdx.y;
    int t = threadIdx.x;
    int k0 = kc * 128;
    if (t < 128) {
        int k = k0 + t;
        float v = 0.f;
        if (k < D_) {
            float s = 0.f;
            for (int pi = 0; pi < NSB_; ++pi) s += pp[((size_t)pi * B_ + b) * D_ + k];
            v = s * (1.0f / S_);
        } else if (k < D_ + NMOD) v = rel[b * NMOD + (k - D_)];
        else if (k < RIN_)        v = reg[b * NREG + (k - D_ - NMOD)];
        rin[t] = v;
    }
    __syncthreads();
    int h = t & 127, half = t >> 7;
    float acc = 0.f;
#pragma unroll 8
    for (int i = 0; i < 64; ++i) {
        int kk = 2 * i + half;
        int k = k0 + kk;
        if (k < RIN_) acc += rin[kk] * w1[(size_t)k * HID_ + h];
    }
    red[t] = acc;
    __syncthreads();
    if (t < 128)
        hacc2[((size_t)b * KC_ + kc) * HID_ + t] = red[t] + red[t + 128];
}

__global__ void router_finish_kernel(const float* __restrict__ hacc2, const float* __restrict__ b1,
                                     const float* __restrict__ w2, const float* __restrict__ b2,
                                     int* __restrict__ top, float* __restrict__ bal_out) {
    __shared__ float h_lds[B_][HID_];
    __shared__ float logit[B_][E_];
    __shared__ float probs[B_][E_];
    int t = threadIdx.x; // 128
    for (int b = 0; b < B_; ++b) {
        float v = b1[t];
        for (int j = 0; j < KC_; ++j) v += hacc2[((size_t)b * KC_ + j) * HID_ + t];
        float u = 0.7978845608028654f * (v + 0.044715f * v * v * v); // tanh-GELU
        h_lds[b][t] = 0.5f * v * (1.0f + tanhf(u));
    }
    __syncthreads();
    if (t < B_ * E_) {
        int b = t >> 2, e = t & 3;
        float acc = b2[e];
        for (int j = 0; j < HID_; ++j) acc += h_lds[b][j] * w2[j * E_ + e];
        logit[b][e] = acc;
    }
    __syncthreads();
    if (t < B_) {
        int b = t;
        float m = logit[b][0]; int arg = 0;
        for (int e = 1; e < E_; ++e) if (logit[b][e] > m) { m = logit[b][e]; arg = e; }
        float s = 0.f, pv[E_];
        for (int e = 0; e < E_; ++e) { pv[e] = expf(logit[b][e] - m); s += pv[e]; }
        for (int e = 0; e < E_; ++e) probs[b][e] = pv[e] / s;
        top[b] = arg;
    }
    __syncthreads();
    if (t == 0) {
        float bal = 0.f;
        for (int e = 0; e < E_; ++e) {
            float avg = 0.25f * (probs[0][e] + probs[1][e] + probs[2][e] + probs[3][e]);
            bal += avg * avg;
        }
        *bal_out = 0.01f * E_ * bal;
    }
}

// out[b,s,o] = 2 * sum_r xr_bf[top[b]][b,s,r] * B_bf[e,o,r]
__global__ __launch_bounds__(256) void out_kernel(const ushort* __restrict__ xr_bf,
                                                  const ushort* __restrict__ Bbf,
                                                  const int* __restrict__ top,
                                                  float* __restrict__ out) {
    __shared__ ushort xrs[64][72];
    __shared__ ushort bs[128][72];
    int b  = blockIdx.z;
    int e  = top[b];
    int s0 = blockIdx.x * 64, o0 = blockIdx.y * 128;
    int t = threadIdx.x, lane = t & 63, w = t >> 6;
    const ushort* xrb = xr_bf + (((size_t)e * B_ + b) * S_ + s0) * R_;
#pragma unroll
    for (int i = 0; i < 2; ++i) {                   // stage xr 64x64 bf16
        int lin = t + 256 * i; int row = lin >> 3, cq = lin & 7;
        int4 v = *(const int4*)(xrb + (size_t)row * R_ + cq * 8);
        *(int4*)&xrs[row][cq * 8] = v;
    }
    const ushort* Bb = Bbf + (size_t)e * OUT_ * R_ + (size_t)o0 * R_;
#pragma unroll
    for (int i = 0; i < 4; ++i) {                   // stage B 128x64 bf16
        int lin = t + 256 * i; int row = lin >> 3, cq = lin & 7;
        int4 v = *(const int4*)(Bb + (size_t)row * R_ + cq * 8);
        *(int4*)&bs[row][cq * 8] = v;
    }
    __syncthreads();
    int mrow = w * 16 + (lane & 15);
    int koff = (lane >> 4) * 8;
    f32x4 acc[8] = {};
#pragma unroll
    for (int kk = 0; kk < 2; ++kk) {
        short8 af = *(const short8*)&xrs[mrow][kk * 32 + koff];
#pragma unroll
        for (int n = 0; n < 8; ++n) {
            short8 bf = *(const short8*)&bs[n * 16 + (lane & 15)][kk * 32 + koff];
            acc[n] = __builtin_amdgcn_mfma_f32_16x16x32_bf16(af, bf, acc[n], 0, 0, 0);
        }
    }
    int col0  = lane & 15;
    int rbase = (lane >> 4) << 2;
    float* ob = out + ((size_t)b * S_ + s0 + w * 16) * OUT_ + o0;
#pragma unroll
    for (int n = 0; n < 8; ++n)
#pragma unroll
        for (int i = 0; i < 4; ++i)
            ob[(size_t)(rbase + i) * OUT_ + n * 16 + col0] = acc[n][i] * SCALING_;
}

extern "C" void kernel_launch(void* const* d_in, const int* in_sizes, int n_in,
                              void* d_out, int out_size, void* d_ws, size_t ws_size,
                              hipStream_t stream) {
    const float* x   = (const float*)d_in[0];
    const float* rel = (const float*)d_in[1];
    const float* reg = (const float*)d_in[2];
    const float* lA  = (const float*)d_in[3];
    const float* lB  = (const float*)d_in[4];
    const float* w1  = (const float*)d_in[5];
    const float* b1  = (const float*)d_in[6];
    const float* w2  = (const float*)d_in[7];
    const float* b2  = (const float*)d_in[8];
    float* out = (float*)d_out;
    float* ws  = (float*)d_ws;

    float*  pp    = ws + WS_PP;
    float*  hacc2 = ws + WS_HACC2;
    int*    top   = (int*)(ws + WS_TOP);
    ushort* Abf   = (ushort*)(ws + WS_ABF);
    ushort* Bbf   = (ushort*)(ws + WS_BBF);
    ushort* xrb   = (ushort*)(ws + WS_XRB);
    ushort* xbf   = (ushort*)(ws + WS_XBF);

    cvt_w_kernel<<<2 * (E_ * R_ * D_ / 4) / 256, 256, 0, stream>>>(lA, lB, Abf, Bbf);
    cvtx_pool_kernel<<<dim3(NSB_, B_), 512, 0, stream>>>(x, xbf, pp);
    xe_kernel<<<dim3(S_ / 64, B_, E_), 512, 0, stream>>>(xbf, Abf, xrb);
    router_h_kernel<<<dim3(B_, KC_), 256, 0, stream>>>(pp, rel, reg, w1, hacc2);
    router_finish_kernel<<<1, 128, 0, stream>>>(hacc2, b1, w2, b2, top,
                                                out + (size_t)out_size - 1);
    out_kernel<<<dim3(S_ / 64, OUT_ / 128, B_), 256, 0, stream>>>(xrb, Bbf, top, out);
}